// Round 1
// baseline (687.770 us; speedup 1.0000x reference)
//
#include <hip/hip_runtime.h>
#include <stdint.h>
#include <math.h>

// Problem constants (fixed by the reference)
#define NH   16
#define HDIM 64
#define SEQ  2048
#define DM   1024
#define NB   2
#define MTOK (NB * SEQ)   // 4096

typedef __bf16 bf16x8 __attribute__((ext_vector_type(8)));  // 4 VGPRs, MFMA A/B frag
typedef float  f32x4  __attribute__((ext_vector_type(4)));  // MFMA C/D frag

__device__ __forceinline__ unsigned short f2bf(float f) {
  union { float f; unsigned int u; } c; c.f = f;
  unsigned int u = c.u;
  return (unsigned short)((u + 0x7FFFu + ((u >> 16) & 1u)) >> 16);  // RNE
}
__device__ __forceinline__ float bf2f(unsigned short s) {
  union { unsigned int u; float f; } c; c.u = ((unsigned int)s) << 16;
  return c.f;
}

// ---------------------------------------------------------------- casts
__global__ void cast_f32_to_bf16(const float* __restrict__ src,
                                 unsigned short* __restrict__ dst, int n4) {
  int i = blockIdx.x * blockDim.x + threadIdx.x;
  if (i >= n4) return;
  float4 v = reinterpret_cast<const float4*>(src)[i];
  ushort4 o;
  o.x = f2bf(v.x); o.y = f2bf(v.y); o.z = f2bf(v.z); o.w = f2bf(v.w);
  reinterpret_cast<ushort4*>(dst)[i] = o;
}

// ---------------------------------------------------------------- GEMM (NT): C[m,n] = sum_k A[m,k]*B[n,k]
// m93-verified structure: 128x128 tile, BK=32, 4 waves each 64x64 (4x4 of 16x16x32 MFMA).
// MODE 0: scatter into Q/K/V [B,H,S,64] bf16.  MODE 1: fp32 out + bias, row-major.
template <int MODE>
__global__ __launch_bounds__(256, 2) void gemm_bt(
    const unsigned short* __restrict__ A,   // [M,K] bf16 bits
    const unsigned short* __restrict__ B,   // [N,K] bf16 bits
    unsigned short* __restrict__ qo, unsigned short* __restrict__ ko,
    unsigned short* __restrict__ vo,
    float* __restrict__ co, const float* __restrict__ bias,
    int M, int N, int K) {
  __shared__ __align__(16) unsigned short As[128 * 32];
  __shared__ __align__(16) unsigned short Bs[128 * 32];

  const int tid  = threadIdx.x;
  const int lane = tid & 63;
  const int wave = tid >> 6;
  const int l15  = lane & 15;
  const int quad = lane >> 4;
  const int wm   = (wave >> 1) * 64;
  const int wn   = (wave & 1) * 64;
  const int m0   = blockIdx.x * 128;
  const int n0   = blockIdx.y * 128;

  f32x4 acc[4][4];
#pragma unroll
  for (int a = 0; a < 4; ++a)
#pragma unroll
    for (int b = 0; b < 4; ++b) acc[a][b] = f32x4{0.f, 0.f, 0.f, 0.f};

  for (int k0 = 0; k0 < K; k0 += 32) {
    __syncthreads();
#pragma unroll
    for (int s = 0; s < 2; ++s) {             // 512 16B chunks / 256 threads
      const int c   = tid + s * 256;
      const int row = c >> 2;
      const int col = (c & 3) * 8;
      const uint4 av = *reinterpret_cast<const uint4*>(A + (size_t)(m0 + row) * K + k0 + col);
      const uint4 bv = *reinterpret_cast<const uint4*>(B + (size_t)(n0 + row) * K + k0 + col);
      *reinterpret_cast<uint4*>(As + row * 32 + col) = av;
      *reinterpret_cast<uint4*>(Bs + row * 32 + col) = bv;
    }
    __syncthreads();

    bf16x8 af[4], bfr[4];
#pragma unroll
    for (int t = 0; t < 4; ++t) {
      // A frag: m = lane&15, k = quad*8+j  (verified m89/m91 layout)
      af[t]  = *reinterpret_cast<const bf16x8*>(As + (wm + t * 16 + l15) * 32 + quad * 8);
      bfr[t] = *reinterpret_cast<const bf16x8*>(Bs + (wn + t * 16 + l15) * 32 + quad * 8);
    }
#pragma unroll
    for (int ti = 0; ti < 4; ++ti)
#pragma unroll
      for (int tj = 0; tj < 4; ++tj)
        acc[ti][tj] = __builtin_amdgcn_mfma_f32_16x16x32_bf16(af[ti], bfr[tj], acc[ti][tj], 0, 0, 0);
  }

  // C/D layout: col = lane&15, row = quad*4 + reg (verified m89/m91)
#pragma unroll
  for (int ti = 0; ti < 4; ++ti) {
#pragma unroll
    for (int tj = 0; tj < 4; ++tj) {
#pragma unroll
      for (int r = 0; r < 4; ++r) {
        const int m = m0 + wm + ti * 16 + quad * 4 + r;
        const int n = n0 + wn + tj * 16 + l15;
        const float v = acc[ti][tj][r];
        if (MODE == 0) {
          const int which = n >> 10;          // 0:q 1:k 2:v  (tiles never straddle: 1024%128==0)
          const int n1 = n & 1023;
          const int h = n1 >> 6, d = n1 & 63;
          const int b = m >> 11, s = m & 2047;
          const size_t idx = ((size_t)(b * NH + h) * SEQ + s) * HDIM + d;
          const unsigned short ov = f2bf(v);
          if (which == 0)      qo[idx] = ov;
          else if (which == 1) ko[idx] = ov;
          else                 vo[idx] = ov;
        } else {
          co[(size_t)m * N + n] = v + bias[n];
        }
      }
    }
  }
}

// ---------------------------------------------------------------- flash attention (fp32 compute, bf16 in/out)
// grid: (qt, bh). 64-query tile, k-tiles of 64, online softmax.
// Thread (i=tid>>4, j=tid&15) owns S/P rows 4i+r, cols 4j+c; O rows 4i+r, dims 4j+c.
__global__ __launch_bounds__(256, 2) void flash_attn(
    const unsigned short* __restrict__ Qb,
    const unsigned short* __restrict__ Kb,
    const unsigned short* __restrict__ Vb,
    unsigned short* __restrict__ ctx) {
  __shared__ __align__(16) float Qs[64 * 64];   // [q][d], pre-scaled by 1/8
  __shared__ __align__(16) float Kt[64 * 64];   // [d][k]  (transposed -> conflict-free score reads)
  __shared__ __align__(16) float Vs[64 * 64];   // [k][d]
  __shared__ __align__(16) float Ps[64 * 64];   // [q][k]

  const int tid = threadIdx.x;
  const int qt  = gridDim.x - 1 - blockIdx.x;   // heavy (long-loop) blocks first
  const int bh  = blockIdx.y;
  const int q0  = qt * 64;
  const int i   = tid >> 4;
  const int j   = tid & 15;

  const size_t base = (size_t)bh * SEQ * HDIM;

  // stage Q, scaled by 1/sqrt(64)
#pragma unroll
  for (int s = 0; s < 2; ++s) {
    const int c = tid + s * 256;
    const int row = c >> 3, d0 = (c & 7) * 8;
    const uint4 v = *reinterpret_cast<const uint4*>(Qb + base + (size_t)(q0 + row) * HDIM + d0);
    const unsigned short* u = reinterpret_cast<const unsigned short*>(&v);
#pragma unroll
    for (int e = 0; e < 8; ++e) Qs[row * 64 + d0 + e] = bf2f(u[e]) * 0.125f;
  }

  float o[4][4];
  float mrow[4], lrow[4];
#pragma unroll
  for (int r = 0; r < 4; ++r) {
    mrow[r] = -INFINITY; lrow[r] = 0.f;
#pragma unroll
    for (int c = 0; c < 4; ++c) o[r][c] = 0.f;
  }

  for (int kt = 0; kt <= qt; ++kt) {
    __syncthreads();   // prev iter done reading Kt/Vs/Ps
#pragma unroll
    for (int s = 0; s < 2; ++s) {
      const int c = tid + s * 256;
      const int key = c >> 3, d0 = (c & 7) * 8;
      const uint4 kv = *reinterpret_cast<const uint4*>(Kb + base + (size_t)(kt * 64 + key) * HDIM + d0);
      const uint4 vv = *reinterpret_cast<const uint4*>(Vb + base + (size_t)(kt * 64 + key) * HDIM + d0);
      const unsigned short* ku = reinterpret_cast<const unsigned short*>(&kv);
      const unsigned short* vu = reinterpret_cast<const unsigned short*>(&vv);
#pragma unroll
      for (int e = 0; e < 8; ++e) {
        Kt[(d0 + e) * 64 + key] = bf2f(ku[e]);
        Vs[key * 64 + d0 + e]   = bf2f(vu[e]);
      }
    }
    __syncthreads();

    // S = Q Kt   (per-thread 4x4, float4 LDS reads: Q broadcast, Kt lane-contiguous)
    float sc[4][4];
#pragma unroll
    for (int r = 0; r < 4; ++r)
#pragma unroll
      for (int c = 0; c < 4; ++c) sc[r][c] = 0.f;

    for (int d0 = 0; d0 < 64; d0 += 4) {
      float qa[4][4], ka[4][4];
#pragma unroll
      for (int r = 0; r < 4; ++r) {
        const float4 t = *reinterpret_cast<const float4*>(&Qs[(4 * i + r) * 64 + d0]);
        qa[r][0] = t.x; qa[r][1] = t.y; qa[r][2] = t.z; qa[r][3] = t.w;
      }
#pragma unroll
      for (int dd = 0; dd < 4; ++dd) {
        const float4 t = *reinterpret_cast<const float4*>(&Kt[(d0 + dd) * 64 + 4 * j]);
        ka[dd][0] = t.x; ka[dd][1] = t.y; ka[dd][2] = t.z; ka[dd][3] = t.w;
      }
#pragma unroll
      for (int r = 0; r < 4; ++r)
#pragma unroll
        for (int dd = 0; dd < 4; ++dd)
#pragma unroll
          for (int c = 0; c < 4; ++c)
            sc[r][c] = fmaf(qa[r][dd], ka[dd][c], sc[r][c]);
    }

    if (kt == qt) {  // causal mask on the diagonal tile
#pragma unroll
      for (int r = 0; r < 4; ++r)
#pragma unroll
        for (int c = 0; c < 4; ++c)
          if (4 * j + c > 4 * i + r) sc[r][c] = -INFINITY;
    }

    // online softmax; row owned by the 16 lanes sharing i (shfl_xor over j)
#pragma unroll
    for (int r = 0; r < 4; ++r) {
      float mx = fmaxf(fmaxf(sc[r][0], sc[r][1]), fmaxf(sc[r][2], sc[r][3]));
#pragma unroll
      for (int off = 1; off < 16; off <<= 1) mx = fmaxf(mx, __shfl_xor(mx, off, 64));
      const float mnew  = fmaxf(mrow[r], mx);
      const float alpha = __expf(mrow[r] - mnew);   // first tile: exp(-inf)=0
      mrow[r] = mnew;
      float rs = 0.f;
#pragma unroll
      for (int c = 0; c < 4; ++c) {
        const float p = __expf(sc[r][c] - mnew);    // masked: exp(-inf)=0
        sc[r][c] = p; rs += p;
      }
#pragma unroll
      for (int off = 1; off < 16; off <<= 1) rs += __shfl_xor(rs, off, 64);
      lrow[r] = lrow[r] * alpha + rs;
#pragma unroll
      for (int c = 0; c < 4; ++c) o[r][c] *= alpha;
    }

    // P -> LDS for the PV pass
#pragma unroll
    for (int r = 0; r < 4; ++r) {
      float4 t; t.x = sc[r][0]; t.y = sc[r][1]; t.z = sc[r][2]; t.w = sc[r][3];
      *reinterpret_cast<float4*>(&Ps[(4 * i + r) * 64 + 4 * j]) = t;
    }
    __syncthreads();

    // O += P V
    for (int k0 = 0; k0 < 64; k0 += 4) {
      float pa[4][4], va[4][4];
#pragma unroll
      for (int r = 0; r < 4; ++r) {
        const float4 t = *reinterpret_cast<const float4*>(&Ps[(4 * i + r) * 64 + k0]);
        pa[r][0] = t.x; pa[r][1] = t.y; pa[r][2] = t.z; pa[r][3] = t.w;
      }
#pragma unroll
      for (int kk = 0; kk < 4; ++kk) {
        const float4 t = *reinterpret_cast<const float4*>(&Vs[(k0 + kk) * 64 + 4 * j]);
        va[kk][0] = t.x; va[kk][1] = t.y; va[kk][2] = t.z; va[kk][3] = t.w;
      }
#pragma unroll
      for (int r = 0; r < 4; ++r)
#pragma unroll
        for (int kk = 0; kk < 4; ++kk)
#pragma unroll
          for (int c = 0; c < 4; ++c)
            o[r][c] = fmaf(pa[r][kk], va[kk][c], o[r][c]);
    }
  }

  // epilogue: ctx[b, s, h*64+d] bf16, normalized
  const int b = bh >> 4, h = bh & 15;
#pragma unroll
  for (int r = 0; r < 4; ++r) {
    const float inv = 1.f / lrow[r];
    const int srow = q0 + 4 * i + r;
    const size_t ob = ((size_t)(b * SEQ + srow)) * DM + h * HDIM + 4 * j;
#pragma unroll
    for (int c = 0; c < 4; ++c) ctx[ob + c] = f2bf(o[r][c] * inv);
  }
}

// ---------------------------------------------------------------- launch
extern "C" void kernel_launch(void* const* d_in, const int* in_sizes, int n_in,
                              void* d_out, int out_size, void* d_ws, size_t ws_size,
                              hipStream_t stream) {
  const float* x  = (const float*)d_in[0];
  const float* wq = (const float*)d_in[1];
  const float* wk = (const float*)d_in[2];
  const float* wv = (const float*)d_in[3];
  const float* wo = (const float*)d_in[4];
  const float* bo = (const float*)d_in[5];
  float* out = (float*)d_out;

  // ws layout (48 MB total)
  char* ws = (char*)d_ws;
  unsigned short* xb    = (unsigned short*)(ws);                    // [4096,1024]    8 MB
  unsigned short* wqkvb = (unsigned short*)(ws + (8ull  << 20));    // [3072,1024]    6 MB
  unsigned short* wob   = (unsigned short*)(ws + (14ull << 20));    // [1024,1024]    2 MB
  unsigned short* Qb    = (unsigned short*)(ws + (16ull << 20));    // [32,2048,64]   8 MB
  unsigned short* Kb    = (unsigned short*)(ws + (24ull << 20));    // 8 MB
  unsigned short* Vb    = (unsigned short*)(ws + (32ull << 20));    // 8 MB
  unsigned short* ctxb  = (unsigned short*)(ws + (40ull << 20));    // [4096,1024]    8 MB

  cast_f32_to_bf16<<<4096, 256, 0, stream>>>(x,  xb,                 MTOK * DM / 4);
  cast_f32_to_bf16<<<1024, 256, 0, stream>>>(wq, wqkvb,              DM * DM / 4);
  cast_f32_to_bf16<<<1024, 256, 0, stream>>>(wk, wqkvb + DM * DM,    DM * DM / 4);
  cast_f32_to_bf16<<<1024, 256, 0, stream>>>(wv, wqkvb + 2 * DM * DM, DM * DM / 4);
  cast_f32_to_bf16<<<1024, 256, 0, stream>>>(wo, wob,                DM * DM / 4);

  dim3 g1(MTOK / 128, (3 * DM) / 128);   // 32 x 24
  gemm_bt<0><<<g1, 256, 0, stream>>>(xb, wqkvb, Qb, Kb, Vb, nullptr, nullptr,
                                     MTOK, 3 * DM, DM);

  dim3 g2(SEQ / 64, NB * NH);            // 32 x 32
  flash_attn<<<g2, 256, 0, stream>>>(Qb, Kb, Vb, ctxb);

  dim3 g3(MTOK / 128, DM / 128);         // 32 x 8
  gemm_bt<1><<<g3, 256, 0, stream>>>(ctxb, wob, nullptr, nullptr, nullptr, out, bo,
                                     MTOK, DM, DM);
}

// Round 2
// 221.432 us; speedup vs baseline: 3.1060x; 3.1060x over previous
//
#include <hip/hip_runtime.h>
#include <stdint.h>
#include <math.h>

// Problem constants (fixed by the reference)
#define NH   16
#define HDIM 64
#define SEQ  2048
#define DM   1024
#define NB   2
#define MTOK (NB * SEQ)   // 4096

typedef __bf16 bf16x8 __attribute__((ext_vector_type(8)));  // 4 VGPRs, MFMA A/B frag
typedef float  f32x4  __attribute__((ext_vector_type(4)));  // MFMA C/D frag

__device__ __forceinline__ unsigned short f2bf(float f) {
  union { float f; unsigned int u; } c; c.f = f;
  unsigned int u = c.u;
  return (unsigned short)((u + 0x7FFFu + ((u >> 16) & 1u)) >> 16);  // RNE
}

// async global->LDS, 16B per lane. LDS dest = wave-uniform base + lane*16 (m104/m108).
__device__ __forceinline__ void async_copy16(const void* g, void* l) {
  __builtin_amdgcn_global_load_lds((__attribute__((address_space(1))) void*)g,
                                   (__attribute__((address_space(3))) void*)l,
                                   16, 0, 0);
}

// ---------------------------------------------------------------- casts
__global__ void cast_f32_to_bf16(const float* __restrict__ src,
                                 unsigned short* __restrict__ dst, int n4) {
  int i = blockIdx.x * blockDim.x + threadIdx.x;
  if (i >= n4) return;
  float4 v = reinterpret_cast<const float4*>(src)[i];
  ushort4 o;
  o.x = f2bf(v.x); o.y = f2bf(v.y); o.z = f2bf(v.z); o.w = f2bf(v.w);
  reinterpret_cast<ushort4*>(dst)[i] = o;
}

// ---------------------------------------------------------------- GEMM (NT): C[m,n] = sum_k A[m,k]*B[n,k]
// m97 structure: 128x128 tile, BK=32, global_load_lds width-16 staging.
// MODE 0: Q (pre-scaled 1/8) / K -> [B,H,S,64] bf16; V -> transposed [B,H,64,S] bf16.
// MODE 1: fp32 out + bias, row-major.
template <int MODE>
__global__ __launch_bounds__(256, 2) void gemm_bt(
    const unsigned short* __restrict__ A,   // [M,K] bf16 bits
    const unsigned short* __restrict__ B,   // [N,K] bf16 bits
    unsigned short* __restrict__ qo, unsigned short* __restrict__ ko,
    unsigned short* __restrict__ vo,        // vo is V^T [B,H,64,SEQ]
    float* __restrict__ co, const float* __restrict__ bias,
    int M, int N, int K) {
  __shared__ __align__(16) unsigned short As[128 * 32];
  __shared__ __align__(16) unsigned short Bs[128 * 32];

  const int tid  = threadIdx.x;
  const int lane = tid & 63;
  const int wave = tid >> 6;
  const int l15  = lane & 15;
  const int quad = lane >> 4;
  const int wm   = (wave >> 1) * 64;
  const int wn   = (wave & 1) * 64;
  const int m0   = blockIdx.x * 128;
  const int n0   = blockIdx.y * 128;

  f32x4 acc[4][4];
#pragma unroll
  for (int a = 0; a < 4; ++a)
#pragma unroll
    for (int b = 0; b < 4; ++b) acc[a][b] = f32x4{0.f, 0.f, 0.f, 0.f};

  for (int k0 = 0; k0 < K; k0 += 32) {
    __syncthreads();
#pragma unroll
    for (int s = 0; s < 2; ++s) {             // 512 16B chunks / 256 threads
      const int c   = tid + s * 256;
      const int row = c >> 2;
      const int col = (c & 3) * 8;
      // LDS element offset for chunk c is c*8 == row*32+col; wave-uniform part:
      unsigned short* lA = As + ((size_t)wave * 64 + s * 256) * 8;
      unsigned short* lB = Bs + ((size_t)wave * 64 + s * 256) * 8;
      async_copy16(A + (size_t)(m0 + row) * K + k0 + col, lA);
      async_copy16(B + (size_t)(n0 + row) * K + k0 + col, lB);
    }
    __syncthreads();

    bf16x8 af[4], bfr[4];
#pragma unroll
    for (int t = 0; t < 4; ++t) {
      // A frag: m = lane&15, k = quad*8+j  (verified m89/m91 layout)
      af[t]  = *reinterpret_cast<const bf16x8*>(As + (wm + t * 16 + l15) * 32 + quad * 8);
      bfr[t] = *reinterpret_cast<const bf16x8*>(Bs + (wn + t * 16 + l15) * 32 + quad * 8);
    }
#pragma unroll
    for (int ti = 0; ti < 4; ++ti)
#pragma unroll
      for (int tj = 0; tj < 4; ++tj)
        acc[ti][tj] = __builtin_amdgcn_mfma_f32_16x16x32_bf16(af[ti], bfr[tj], acc[ti][tj], 0, 0, 0);
  }

  // C/D layout: col = lane&15, row = quad*4 + reg (verified m89/m91)
#pragma unroll
  for (int ti = 0; ti < 4; ++ti) {
#pragma unroll
    for (int tj = 0; tj < 4; ++tj) {
      const int mb = m0 + wm + ti * 16 + quad * 4;   // rows mb..mb+3
      const int n  = n0 + wn + tj * 16 + l15;
      if (MODE == 0) {
        const int which = n >> 10;          // 0:q 1:k 2:v
        const int n1 = n & 1023;
        const int h = n1 >> 6, d = n1 & 63;
        const int b = mb >> 11, s = mb & 2047;
        if (which == 0) {
          const size_t idx = ((size_t)(b * NH + h) * SEQ + s) * HDIM + d;
#pragma unroll
          for (int r = 0; r < 4; ++r) qo[idx + (size_t)r * HDIM] = f2bf(acc[ti][tj][r] * 0.125f);
        } else if (which == 1) {
          const size_t idx = ((size_t)(b * NH + h) * SEQ + s) * HDIM + d;
#pragma unroll
          for (int r = 0; r < 4; ++r) ko[idx + (size_t)r * HDIM] = f2bf(acc[ti][tj][r]);
        } else {
          // V^T: [b,h,d,s] — 4 consecutive s per lane -> packed 8B store
          const size_t idx = ((size_t)(b * NH + h) * HDIM + d) * SEQ + s;
          ushort4 pk;
          pk.x = f2bf(acc[ti][tj][0]); pk.y = f2bf(acc[ti][tj][1]);
          pk.z = f2bf(acc[ti][tj][2]); pk.w = f2bf(acc[ti][tj][3]);
          *reinterpret_cast<ushort4*>(vo + idx) = pk;
        }
      } else {
#pragma unroll
        for (int r = 0; r < 4; ++r)
          co[(size_t)(mb + r) * N + n] = acc[ti][tj][r] + bias[n];
      }
    }
  }
}

// ---------------------------------------------------------------- MFMA flash attention
// Block = 4 waves, Q-tile 64 (16 q-rows per wave), k-tiles of 64 keys.
// S^T = K·Q^T per wave: lane owns q = q0+wave*16+(lane&15); softmax state scalar/lane.
// P transposed to LDS (bf16), PV via A=P rows, B=V^T rows. Causal via -inf init.
#define KS_STRIDE 80   // 64 + 16 pad: bank-balanced frag reads, 16B-aligned rows
#define PT_STRIDE 80

__global__ __launch_bounds__(256, 4) void flash_attn_mfma(
    const unsigned short* __restrict__ Qb,   // [bh][s][64], pre-scaled by 1/8
    const unsigned short* __restrict__ Kb,   // [bh][s][64]
    const unsigned short* __restrict__ Vtg,  // [bh][d][2048]  (V^T)
    unsigned short* __restrict__ ctx) {      // [b][s][1024] bf16
  __shared__ __align__(16) unsigned short Ks[64 * KS_STRIDE];
  __shared__ __align__(16) unsigned short Vt[64 * KS_STRIDE];
  __shared__ __align__(16) unsigned short Pt[4][16 * PT_STRIDE];

  const int tid  = threadIdx.x;
  const int qt   = gridDim.x - 1 - blockIdx.x;  // heavy (long-loop) blocks first
  const int bh   = blockIdx.y;
  const int q0   = qt * 64;
  const int lane = tid & 63;
  const int wave = tid >> 6;
  const int l15  = lane & 15;
  const int quad = lane >> 4;

  const size_t baseQK = (size_t)bh * SEQ * HDIM;
  const size_t baseV  = (size_t)bh * HDIM * SEQ;

  // Q fragments (B-operand of S^T): lane holds Q[q = q0+wave*16+l15][k = s*32+quad*8+j]
  bf16x8 qf[2];
  {
    const unsigned short* qp = Qb + baseQK + (size_t)(q0 + wave * 16 + l15) * HDIM + quad * 8;
    qf[0] = *reinterpret_cast<const bf16x8*>(qp);
    qf[1] = *reinterpret_cast<const bf16x8*>(qp + 32);
  }

  float m_s = -INFINITY, l_s = 0.f;
  f32x4 o[4];   // o[td][r] = O[q=quad*4+r][d=td*16+l15]
#pragma unroll
  for (int td = 0; td < 4; ++td) o[td] = f32x4{0.f, 0.f, 0.f, 0.f};

  for (int kt = 0; kt <= qt; ++kt) {
    __syncthreads();   // previous iteration done reading Ks/Vt
    {
      const int row = tid >> 3;
      const int col = (tid & 7) * 8;
#pragma unroll
      for (int s = 0; s < 2; ++s) {
        const int r2 = row + s * 32;
        const uint4 kv = *reinterpret_cast<const uint4*>(Kb + baseQK + (size_t)(kt * 64 + r2) * HDIM + col);
        const uint4 vv = *reinterpret_cast<const uint4*>(Vtg + baseV + (size_t)r2 * SEQ + kt * 64 + col);
        *reinterpret_cast<uint4*>(&Ks[r2 * KS_STRIDE + col]) = kv;
        *reinterpret_cast<uint4*>(&Vt[r2 * KS_STRIDE + col]) = vv;
      }
    }
    __syncthreads();

    const int tmax = (kt == qt) ? wave : 3;   // diag: key tiles above wave strip fully masked

    // S^T tiles: st[t][r] = S[key = kt*64 + t*16 + quad*4 + r][q = l15]
    f32x4 st[4];
#pragma unroll
    for (int t = 0; t < 4; ++t) st[t] = f32x4{-INFINITY, -INFINITY, -INFINITY, -INFINITY};
#pragma unroll
    for (int t = 0; t < 4; ++t) {
      if (t <= tmax) {
        f32x4 c = f32x4{0.f, 0.f, 0.f, 0.f};
        const bf16x8 kf0 = *reinterpret_cast<const bf16x8*>(&Ks[(t * 16 + l15) * KS_STRIDE + quad * 8]);
        const bf16x8 kf1 = *reinterpret_cast<const bf16x8*>(&Ks[(t * 16 + l15) * KS_STRIDE + 32 + quad * 8]);
        c = __builtin_amdgcn_mfma_f32_16x16x32_bf16(kf0, qf[0], c, 0, 0, 0);
        c = __builtin_amdgcn_mfma_f32_16x16x32_bf16(kf1, qf[1], c, 0, 0, 0);
        if (kt == qt && t == wave) {   // partial (diagonal) tile: mask key > q
#pragma unroll
          for (int r = 0; r < 4; ++r)
            if (quad * 4 + r > l15) c[r] = -INFINITY;
        }
        st[t] = c;
      }
    }

    // online softmax; q-row = l15, values spread over (t, r, quad)
    float mx = -INFINITY;
#pragma unroll
    for (int t = 0; t < 4; ++t)
#pragma unroll
      for (int r = 0; r < 4; ++r) mx = fmaxf(mx, st[t][r]);
    mx = fmaxf(mx, __shfl_xor(mx, 16, 64));
    mx = fmaxf(mx, __shfl_xor(mx, 32, 64));
    const float mnew  = fmaxf(m_s, mx);
    const float alpha = __expf(m_s - mnew);
    m_s = mnew;

    float rs = 0.f;
#pragma unroll
    for (int t = 0; t < 4; ++t) {
      ushort4 pk;
      float p0 = __expf(st[t][0] - mnew);
      float p1 = __expf(st[t][1] - mnew);
      float p2 = __expf(st[t][2] - mnew);
      float p3 = __expf(st[t][3] - mnew);
      rs += (p0 + p1) + (p2 + p3);
      pk.x = f2bf(p0); pk.y = f2bf(p1); pk.z = f2bf(p2); pk.w = f2bf(p3);
      // P^T stored as P[q=l15][key]: lane writes keys t*16+quad*4..+3 (8B packed)
      *reinterpret_cast<ushort4*>(&Pt[wave][l15 * PT_STRIDE + t * 16 + quad * 4]) = pk;
    }
    rs += __shfl_xor(rs, 16, 64);
    rs += __shfl_xor(rs, 32, 64);
    l_s = l_s * alpha + rs;

    // rescale O by alpha of row q=quad*4+r (alpha uniform across quads per l15)
#pragma unroll
    for (int r = 0; r < 4; ++r) {
      const float ar = __shfl(alpha, quad * 4 + r, 64);
#pragma unroll
      for (int td = 0; td < 4; ++td) o[td][r] *= ar;
    }

    // O += P·V : A-frag = P[q=l15][key=s*32+quad*8+j], B-frag = V^T[d=td*16+l15][key]
#pragma unroll
    for (int s = 0; s < 2; ++s) {
      const bf16x8 pf = *reinterpret_cast<const bf16x8*>(&Pt[wave][l15 * PT_STRIDE + s * 32 + quad * 8]);
#pragma unroll
      for (int td = 0; td < 4; ++td) {
        const bf16x8 vf = *reinterpret_cast<const bf16x8*>(&Vt[(td * 16 + l15) * KS_STRIDE + s * 32 + quad * 8]);
        o[td] = __builtin_amdgcn_mfma_f32_16x16x32_bf16(pf, vf, o[td], 0, 0, 0);
      }
    }
  }

  // epilogue: normalize and write ctx[b][s][h*64+d] bf16
  const float linv = 1.f / l_s;   // for q = l15
  const int b = bh >> 4, h = bh & 15;
#pragma unroll
  for (int r = 0; r < 4; ++r) {
    const float lr = __shfl(linv, quad * 4 + r, 64);
    const int srow = q0 + wave * 16 + quad * 4 + r;
    const size_t ob = (size_t)(b * SEQ + srow) * DM + h * HDIM + l15;
#pragma unroll
    for (int td = 0; td < 4; ++td)
      ctx[ob + td * 16] = f2bf(o[td][r] * lr);
  }
}

// ---------------------------------------------------------------- launch
extern "C" void kernel_launch(void* const* d_in, const int* in_sizes, int n_in,
                              void* d_out, int out_size, void* d_ws, size_t ws_size,
                              hipStream_t stream) {
  const float* x  = (const float*)d_in[0];
  const float* wq = (const float*)d_in[1];
  const float* wk = (const float*)d_in[2];
  const float* wv = (const float*)d_in[3];
  const float* wo = (const float*)d_in[4];
  const float* bo = (const float*)d_in[5];
  float* out = (float*)d_out;

  // ws layout (48 MB total)
  char* ws = (char*)d_ws;
  unsigned short* xb    = (unsigned short*)(ws);                    // [4096,1024]    8 MB
  unsigned short* wqkvb = (unsigned short*)(ws + (8ull  << 20));    // [3072,1024]    6 MB
  unsigned short* wob   = (unsigned short*)(ws + (14ull << 20));    // [1024,1024]    2 MB
  unsigned short* Qb    = (unsigned short*)(ws + (16ull << 20));    // [32,2048,64]   8 MB (pre-scaled)
  unsigned short* Kb    = (unsigned short*)(ws + (24ull << 20));    // [32,2048,64]   8 MB
  unsigned short* Vtg   = (unsigned short*)(ws + (32ull << 20));    // [32,64,2048]   8 MB (V^T)
  unsigned short* ctxb  = (unsigned short*)(ws + (40ull << 20));    // [4096,1024]    8 MB

  cast_f32_to_bf16<<<4096, 256, 0, stream>>>(x,  xb,                  MTOK * DM / 4);
  cast_f32_to_bf16<<<1024, 256, 0, stream>>>(wq, wqkvb,               DM * DM / 4);
  cast_f32_to_bf16<<<1024, 256, 0, stream>>>(wk, wqkvb + DM * DM,     DM * DM / 4);
  cast_f32_to_bf16<<<1024, 256, 0, stream>>>(wv, wqkvb + 2 * DM * DM, DM * DM / 4);
  cast_f32_to_bf16<<<1024, 256, 0, stream>>>(wo, wob,                 DM * DM / 4);

  dim3 g1(MTOK / 128, (3 * DM) / 128);   // 32 x 24
  gemm_bt<0><<<g1, 256, 0, stream>>>(xb, wqkvb, Qb, Kb, Vtg, nullptr, nullptr,
                                     MTOK, 3 * DM, DM);

  dim3 g2(SEQ / 64, NB * NH);            // 32 x 32
  flash_attn_mfma<<<g2, 256, 0, stream>>>(Qb, Kb, Vtg, ctxb);

  dim3 g3(MTOK / 128, DM / 128);         // 32 x 8
  gemm_bt<1><<<g3, 256, 0, stream>>>(ctxb, wob, nullptr, nullptr, nullptr, out, bo,
                                     MTOK, DM, DM);
}